// Round 10
// baseline (476.531 us; speedup 1.0000x reference)
//
#include <hip/hip_runtime.h>

#define NB 4                 // batch
#define GRID_X 640
#define NCELL (GRID_X*GRID_X)      // 409600
#define NWORD (NCELL/32)           // 12800 bitmask words per sample
#define MAXPIL 12000
#define MAXPTS 100
#define NBLOCKS 384                // <= co-resident capacity 512 (launch_bounds 256,2); 128-block margin
#define NTHREADS 256
#define NWAVES (NBLOCKS*NTHREADS/64)               // 1536
#define PPW ((NB*MAXPIL + NWAVES - 1)/NWAVES)      // 32 pillars per wave (contiguous)

typedef unsigned short u16;
typedef unsigned int   u32;

// ---- bf16 round-trip (RTNE) — used ONLY for the pillar-id value write ----
__device__ __forceinline__ float bf16rt(float f) {
    u32 u = __builtin_bit_cast(u32, f);
    u32 r = ((u + 0x7FFFu + ((u >> 16) & 1u)) >> 16) << 16;
    return __builtin_bit_cast(float, r);
}

// value barrier: blocks -ffp-contract=fast from fusing mul into the following sub
__device__ __forceinline__ float opaquef(float x) { asm volatile("" : "+v"(x)); return x; }

// XLA constant-folded reciprocals (bit-exact verified rounds 6-9):
#define R102 0.009765625f
#define RWH  320.000030517578125f          // 0x1.400002p8
__device__ __host__ constexpr float WH_N_C() { return (2.0f*0.16f)/(51.2f-(-51.2f)); }

__device__ __forceinline__ float norm_x(float v) {
    float p = 2.0f*(v + 51.2f) * R102;
    return opaquef(p) - 1.0f;
}
__device__ __forceinline__ float norm_z(float v) {
    float p = 2.0f*(v + 5.0f) * 0.125f;
    return opaquef(p) - 1.0f;
}

__device__ __forceinline__ int cell_of(float xn, float yn) {
    float fx = fminf(fmaxf(floorf((xn + 1.0f) * RWH), 0.0f), 639.0f);
    float fy = fminf(fmaxf(floorf((yn + 1.0f) * RWH), 0.0f), 639.0f);
    return (int)fy * GRID_X + (int)fx;
}

// ---- K0: zero barrier ctrs + occMask + slotCnt; prefill pillars/slotCell ----
// (ctrs zeroed HERE so the grid barrier never depends on poison values)
__global__ void k_init(u32* __restrict__ ws, float* __restrict__ pillars_f,
                       int* __restrict__ slotCell) {
    int i = blockIdx.x*blockDim.x + threadIdx.x;
    if (i < 8 + NB*NWORD + NB*MAXPIL) ws[i] = 0u;          // ctr[8] + occMask + slotCnt
    if (i < NB*MAXPIL) { slotCell[i] = -1; pillars_f[i] = -1.0f; }
}

// ---- device-scope grid barrier (counters pre-zeroed by k_init) ----
__device__ __forceinline__ void gridbar(u32* ctr) {
    __syncthreads();
    if (threadIdx.x == 0) {
        __threadfence();
        __hip_atomic_fetch_add(ctr, 1u, __ATOMIC_ACQ_REL, __HIP_MEMORY_SCOPE_AGENT);
        while (__hip_atomic_load(ctr, __ATOMIC_ACQUIRE, __HIP_MEMORY_SCOPE_AGENT) < (u32)NBLOCKS)
            __builtin_amdgcn_s_sleep(2);
        __threadfence();
    }
    __syncthreads();
}

// ---- K1: the whole pipeline in one persistent kernel ----
__global__ __launch_bounds__(NTHREADS, 2)
void k_fused(const float4* __restrict__ pc, int P,
             u32* __restrict__ ctrs, u32* __restrict__ occMask,
             int* __restrict__ slotCnt, int* __restrict__ wordPrefix,
             int* __restrict__ slotCell, u16* __restrict__ idx16,
             float* __restrict__ pillars_f, float* __restrict__ out) {
    const int tid0   = blockIdx.x*NTHREADS + threadIdx.x;
    const int stride = NBLOCKS*NTHREADS;

    // ---- P1: occupancy bitmask ----
    for (int i = tid0; i < NB*P; i += stride) {
        float4 pt = pc[i];
        int cell = cell_of(norm_x(pt.x), norm_x(pt.y));
        int b = 0, t = i;
        while (t >= P) { t -= P; ++b; }
        atomicOr(&occMask[b*NWORD + (cell >> 5)], 1u << (cell & 31));
    }
    gridbar(&ctrs[0]);

    // ---- P2: scan (200 virtual blocks; offset via redundant L2-hot popcount) ----
    __shared__ int arr[NTHREADS];
    __shared__ int offs_s;
    if (blockIdx.x < NB*50) {
        int b = blockIdx.x / 50, blk = blockIdx.x % 50, t = threadIdx.x;
        const u32* msk = occMask + b*NWORD;
        int acc = 0;
        for (int w = t; w < blk*256; w += 256) acc += __popc(msk[w]);
        arr[t] = acc;
        __syncthreads();
        for (int d = 128; d > 0; d >>= 1) {
            if (t < d) arr[t] += arr[t + d];
            __syncthreads();
        }
        if (t == 0) offs_s = arr[0];
        __syncthreads();
        u32 m = msk[blk*256 + t];
        int pop = __popc(m);
        arr[t] = pop;
        __syncthreads();
        for (int d = 1; d < 256; d <<= 1) {
            int v = (t >= d) ? arr[t - d] : 0;
            __syncthreads();
            arr[t] += v;
            __syncthreads();
        }
        int prefix = offs_s + arr[t] - pop;     // exclusive
        wordPrefix[b*NWORD + blk*256 + t] = prefix;
        int wbase = (blk*256 + t) << 5;
        while (m) {
            int bit = __ffs(m) - 1;
            m &= m - 1;
            if (prefix < MAXPIL) {
                int cell = wbase + bit;
                slotCell[b*MAXPIL + prefix] = cell;
                pillars_f[b*MAXPIL + prefix] = bf16rt((float)cell);
            }
            ++prefix;
        }
    }
    gridbar(&ctrs[1]);

    // ---- P3: scatter point indices into per-pillar arrival lists ----
    for (int i = tid0; i < NB*P; i += stride) {
        float4 pt = pc[i];
        int cell = cell_of(norm_x(pt.x), norm_x(pt.y));
        int b = 0, p = i;
        while (p >= P) { p -= P; ++b; }
        int w = cell >> 5, bit = cell & 31;
        u32 m = occMask[b*NWORD + w];
        int slot = wordPrefix[b*NWORD + w] + __popc(m & ((1u << bit) - 1u));
        if (slot < MAXPIL) {
            int gq = b*MAXPIL + slot;
            int pos = atomicAdd(&slotCnt[gq], 1);
            if (pos < MAXPTS) idx16[(size_t)gq*MAXPTS + pos] = (u16)p;
        }
    }
    gridbar(&ctrs[2]);

    // ---- P4: one wave per pillar, 32 contiguous pillars/wave, no LDS/barriers ----
    int gwave = tid0 >> 6;
    int lane  = threadIdx.x & 63;
    int gend  = min((gwave + 1)*PPW, NB*MAXPIL);
    for (int g = gwave*PPW; g < gend; ++g) {
        int u = slotCell[g];
        float* outp = out + (size_t)g*900;
        if (u < 0) {                        // empty: pure zero stream
            float4* o4 = (float4*)outp;
            float4 z = make_float4(0.f,0.f,0.f,0.f);
            for (int i = lane; i < 225; i += 64) o4[i] = z;
            continue;
        }
        int b = g / MAXPIL;
        int ntot = slotCnt[g];
        int n = min(ntot, MAXPTS);          // ~5 points/pillar in this dataset
        const u16* lst = idx16 + (size_t)g*MAXPTS;

        float sxv = 0.f, syv = 0.f, szv = 0.f;
        float4 mypt[2]; int myrk[2]; bool act[2];
        #pragma unroll
        for (int c = 0; c < 2; ++c) {       // n <= 100 -> at most 2 chunks of 64
            int j = lane + 64*c;
            act[c] = (j < n);
            myrk[c] = 0;
            if (act[c]) {
                int p = lst[j];
                int rk = 0;                 // rank by original point index (stable order)
                for (int k = 0; k < n; ++k) rk += (lst[k] < (u16)p) ? 1 : 0;
                myrk[c] = rk;
                float4 pt = pc[(size_t)b*P + p];
                mypt[c] = pt;
                sxv += norm_x(pt.x); syv += norm_x(pt.y); szv += norm_z(pt.z);
            }
        }
        for (int m = 1; m < 64; m <<= 1) {
            sxv += __shfl_xor(sxv, m);
            syv += __shfl_xor(syv, m);
            szv += __shfl_xor(szv, m);
        }
        float den = (float)ntot;
        float mx = sxv/den, my = syv/den, mz = szv/den;
        const float wh = WH_N_C();
        float cx = -1.0f + (float)(u % GRID_X)*wh + wh*0.5f;
        float cy = -1.0f + (float)(u / GRID_X)*wh + wh*0.5f;
        #pragma unroll
        for (int c = 0; c < 2; ++c) if (act[c]) {
            float4 pt = mypt[c];
            float xn = norm_x(pt.x), yn = norm_x(pt.y), zn = norm_z(pt.z);
            float* e = outp + myrk[c]*9;    // ranks contiguous: rows fill the front
            e[0] = xn; e[1] = yn; e[2] = zn; e[3] = pt.w;
            e[4] = fabsf(xn - mx); e[5] = fabsf(yn - my); e[6] = fabsf(zn - mz);
            e[7] = cx - xn; e[8] = cy - yn;
        }
        int nd = n*9;
        for (int i = nd + lane; i < 900; i += 64) outp[i] = 0.0f;   // zero tail
    }
}

extern "C" void kernel_launch(void* const* d_in, const int* in_sizes, int n_in,
                              void* d_out, int out_size, void* d_ws, size_t ws_size,
                              hipStream_t stream) {
    const float4* pc = (const float4*)d_in[0];     // f32 x4 per point
    int P = in_sizes[0] / (NB*4);                  // 50000
    float* out = (float*)d_out;                    // f32 output buffer
    float* pillars_f = out + (size_t)NB*MAXPIL*MAXPTS*9;  // second tuple output (f32)

    // workspace layout (~10.4 MB total)
    u32* ctrs      = (u32*)d_ws;                        // 8 barrier words   [zeroed by k_init]
    u32* occMask   = ctrs + 8;                          // NB*NWORD = 51200  [zeroed]
    int* slotCnt   = (int*)(occMask + NB*NWORD);        // NB*MAXPIL = 48000 [zeroed]
    int* wordPrefix= slotCnt + NB*MAXPIL;               // NB*NWORD = 51200
    int* slotCell  = wordPrefix + NB*NWORD;             // NB*MAXPIL = 48000
    u16* idx16     = (u16*)(slotCell + NB*MAXPIL);      // NB*MAXPIL*MAXPTS u16 = 9.6 MB

    const int nZero = 8 + NB*NWORD + NB*MAXPIL;         // 99208 words
    k_init<<<(nZero+255)/256, 256, 0, stream>>>((u32*)d_ws, pillars_f, slotCell);
    k_fused<<<NBLOCKS, NTHREADS, 0, stream>>>(pc, P, ctrs, occMask, slotCnt,
                                              wordPrefix, slotCell, idx16, pillars_f, out);
}

// Round 11
// 245.495 us; speedup vs baseline: 1.9411x; 1.9411x over previous
//
#include <hip/hip_runtime.h>

#define NB 4                 // batch
#define GRID_X 640
#define NCELL (GRID_X*GRID_X)      // 409600
#define NWORD (NCELL/32)           // 12800 bitmask words per sample
#define MAXPIL 12000
#define MAXPTS 100
#define NBLKA (NWORD/256)          // 50 scan blocks per sample
#define PPB 4                      // pillars per block in k_write (1 wave each)

typedef unsigned short u16;
typedef unsigned int   u32;

// ---- bf16 round-trip (RTNE) — used ONLY for the pillar-id value write ----
__device__ __forceinline__ float bf16rt(float f) {
    u32 u = __builtin_bit_cast(u32, f);
    u32 r = ((u + 0x7FFFu + ((u >> 16) & 1u)) >> 16) << 16;
    return __builtin_bit_cast(float, r);
}

// value barrier: blocks -ffp-contract=fast from fusing mul into the following sub
__device__ __forceinline__ float opaquef(float x) { asm volatile("" : "+v"(x)); return x; }

// XLA constant-folded reciprocals (bit-exact verified rounds 6-10):
#define R102 0.009765625f
#define RWH  320.000030517578125f          // 0x1.400002p8
__device__ __host__ constexpr float WH_N_C() { return (2.0f*0.16f)/(51.2f-(-51.2f)); }

__device__ __forceinline__ float norm_x(float v) {
    float p = 2.0f*(v + 51.2f) * R102;
    return opaquef(p) - 1.0f;
}
__device__ __forceinline__ float norm_z(float v) {
    float p = 2.0f*(v + 5.0f) * 0.125f;
    return opaquef(p) - 1.0f;
}

__device__ __forceinline__ int cell_of(float xn, float yn) {
    float fx = fminf(fmaxf(floorf((xn + 1.0f) * RWH), 0.0f), 639.0f);
    float fy = fminf(fmaxf(floorf((yn + 1.0f) * RWH), 0.0f), 639.0f);
    return (int)fy * GRID_X + (int)fx;
}

// ---- K0: zero occMask+slotCnt; prefill pillars=-1.0f, slotCell=-1 ----
__global__ void k_init(int4* __restrict__ ws4, int nw4,
                       float* __restrict__ pillars_f, int* __restrict__ slotCell, int npil) {
    int i = blockIdx.x*blockDim.x + threadIdx.x;
    if (i < nw4) ws4[i] = make_int4(0,0,0,0);
    if (i < npil) { pillars_f[i] = -1.0f; slotCell[i] = -1; }
}

// ---- K1: per-point cell id -> bitmask + pidx cache ----
__global__ void k_mask(const float4* __restrict__ pc, int P,
                       u32* __restrict__ occMask, u32* __restrict__ pidxBuf) {
    int i = blockIdx.x*blockDim.x + threadIdx.x;
    if (i >= NB*P) return;
    float4 pt = pc[i];
    int cell = cell_of(norm_x(pt.x), norm_x(pt.y));
    int b = i / P;
    atomicOr(&occMask[b*NWORD + (cell >> 5)], 1u << (cell & 31));
    pidxBuf[i] = (u32)cell;
}

// ---- K2: self-sufficient scan (200 blocks): each block popcounts its own
//      preceding words (<=50/thread, L2-hot), then prefix-scans its 256 words
//      and emits sorted pillar ids. (pattern correctness-verified in r10 P2) ----
__global__ __launch_bounds__(256) void k_scan(const u32* __restrict__ occMask,
                        int* __restrict__ wordPrefix, float* __restrict__ pillars_f,
                        int* __restrict__ slotCell) {
    __shared__ int arr[256];
    __shared__ int offs_s;
    int b = blockIdx.x / NBLKA, blk = blockIdx.x % NBLKA, t = threadIdx.x;
    const u32* msk = occMask + b*NWORD;
    int acc = 0;
    for (int w = t; w < blk*256; w += 256) acc += __popc(msk[w]);
    arr[t] = acc;
    __syncthreads();
    for (int d = 128; d > 0; d >>= 1) {
        if (t < d) arr[t] += arr[t + d];
        __syncthreads();
    }
    if (t == 0) offs_s = arr[0];
    __syncthreads();
    u32 m = msk[blk*256 + t];
    int pop = __popc(m);
    arr[t] = pop;
    __syncthreads();
    for (int d = 1; d < 256; d <<= 1) {
        int v = (t >= d) ? arr[t - d] : 0;
        __syncthreads();
        arr[t] += v;
        __syncthreads();
    }
    int prefix = offs_s + arr[t] - pop;     // exclusive
    wordPrefix[b*NWORD + blk*256 + t] = prefix;
    int wbase = (blk*256 + t) << 5;
    while (m) {
        int bit = __ffs(m) - 1;
        m &= m - 1;
        if (prefix < MAXPIL) {
            int cell = wbase + bit;
            slotCell[b*MAXPIL + prefix] = cell;
            pillars_f[b*MAXPIL + prefix] = bf16rt((float)cell);
        }
        ++prefix;
    }
}

// ---- K3: scatter point indices into per-pillar arrival lists (pidx cached) ----
__global__ void k_scatter(int P, const u32* __restrict__ pidxBuf,
                          const u32* __restrict__ occMask, const int* __restrict__ wordPrefix,
                          int* __restrict__ slotCnt, u16* __restrict__ idx16) {
    int i = blockIdx.x*blockDim.x + threadIdx.x;
    if (i >= NB*P) return;
    int b = i / P;
    int p = i - b*P;
    int cell = (int)pidxBuf[i];
    int w = cell >> 5, bit = cell & 31;
    u32 m = occMask[b*NWORD + w];
    int slot = wordPrefix[b*NWORD + w] + __popc(m & ((1u << bit) - 1u));
    if (slot >= MAXPIL) return;
    int g = b*MAXPIL + slot;
    int pos = atomicAdd(&slotCnt[g], 1);
    if (pos < MAXPTS) idx16[(size_t)g*MAXPTS + pos] = (u16)p;
}

// ---- K4: 4 pillars/block (256 thr, 1 wave each), per-wave LDS, NO barriers.
//      Ranks are contiguous -> data fills the tile front; tail = register zeros.
//      8 blocks/CU resident (launch_bounds 256,8) = 32 waves/CU. ----
__global__ __launch_bounds__(256, 8) void k_write(const float4* __restrict__ pc, int P,
                        const int* __restrict__ slotCell, const int* __restrict__ slotCnt,
                        const u16* __restrict__ idx16, float* __restrict__ out) {
    __shared__ __align__(16) float tile[PPB][MAXPTS*9 + 4];   // per-wave private regions
    __shared__ int sIdx[PPB][MAXPTS];
    int wv   = threadIdx.x >> 6;
    int lane = threadIdx.x & 63;
    int g = blockIdx.x*PPB + wv;        // b*MAXPIL + slot
    float4* out4 = (float4*)out + (size_t)g*225;
    int u = slotCell[g];
    float4 z = make_float4(0.f,0.f,0.f,0.f);
    if (u < 0) {                        // empty: pure zero stream, no LDS, no sync
        for (int i = lane; i < 225; i += 64) out4[i] = z;
        return;
    }
    int b = g / MAXPIL;
    int ntot = slotCnt[g];
    int n = min(ntot, MAXPTS);          // ~5 points/pillar in this dataset
    const u16* lst = idx16 + (size_t)g*MAXPTS;
    float* mytile = tile[wv];
    int*   myidx  = sIdx[wv];

    for (int j = lane; j < n; j += 64) myidx[j] = lst[j];
    // wave-internal LDS RAW: ordered by compiler-inserted lgkmcnt waits

    float ax = 0.f, ay = 0.f, az = 0.f;
    for (int j = lane; j < n; j += 64) {
        float4 pt = pc[(size_t)b*P + myidx[j]];
        ax += norm_x(pt.x); ay += norm_x(pt.y); az += norm_z(pt.z);
    }
    for (int m = 1; m < 64; m <<= 1) {
        ax += __shfl_xor(ax, m);
        ay += __shfl_xor(ay, m);
        az += __shfl_xor(az, m);
    }
    float den = (float)ntot;
    float mx = ax/den, my = ay/den, mz = az/den;
    const float wh = WH_N_C();
    float cx = -1.0f + (float)(u % GRID_X)*wh + wh*0.5f;
    float cy = -1.0f + (float)(u / GRID_X)*wh + wh*0.5f;

    for (int j = lane; j < n; j += 64) {
        int p = myidx[j];
        int rk = 0;                     // rank by original point index (stable order)
        for (int k = 0; k < n; ++k) rk += (myidx[k] < p) ? 1 : 0;
        float4 pt = pc[(size_t)b*P + p];
        float xn = norm_x(pt.x), yn = norm_x(pt.y), zn = norm_z(pt.z);
        float* e = mytile + rk*9;       // ranks 0..n-1: contiguous front of tile
        e[0] = xn; e[1] = yn; e[2] = zn; e[3] = pt.w;
        e[4] = fabsf(xn - mx); e[5] = fabsf(yn - my); e[6] = fabsf(zn - mz);
        e[7] = cx - xn; e[8] = cy - yn;
    }
    int nd = n*9;
    int nf4 = (nd + 3) >> 2;
    if (lane < nf4*4 - nd) mytile[nd + lane] = 0.f;   // zero the <=3 pad floats

    float4* t4 = (float4*)mytile;
    for (int i = lane; i < 225; i += 64) out4[i] = (i < nf4) ? t4[i] : z;
}

extern "C" void kernel_launch(void* const* d_in, const int* in_sizes, int n_in,
                              void* d_out, int out_size, void* d_ws, size_t ws_size,
                              hipStream_t stream) {
    const float4* pc = (const float4*)d_in[0];     // f32 x4 per point
    int P = in_sizes[0] / (NB*4);                  // 50000
    float* out = (float*)d_out;                    // f32 output buffer
    float* pillars_f = out + (size_t)NB*MAXPIL*MAXPTS*9;  // second tuple output (f32)

    // workspace layout (~11.2 MB total, int units)
    u32* occMask   = (u32*)d_ws;                        // NB*NWORD      = 51200  [zeroed]
    int* slotCnt   = (int*)(occMask + NB*NWORD);        // NB*MAXPIL     = 48000  [zeroed]
    int* wordPrefix= slotCnt + NB*MAXPIL;               // NB*NWORD      = 51200
    int* slotCell  = wordPrefix + NB*NWORD;             // NB*MAXPIL     = 48000
    u32* pidxBuf   = (u32*)(slotCell + NB*MAXPIL);      // NB*P          = 200000
    u16* idx16     = (u16*)(pidxBuf + NB*P);            // NB*MAXPIL*MAXPTS u16 = 9.6 MB

    const int nWs4 = (NB*NWORD + NB*MAXPIL)/4;          // 24,800 int4
    const int npil = NB*MAXPIL;                         // 48,000
    int initThreads = npil > nWs4 ? npil : nWs4;

    k_init<<<(initThreads+255)/256, 256, 0, stream>>>((int4*)occMask, nWs4, pillars_f, slotCell, npil);
    k_mask<<<(NB*P+255)/256, 256, 0, stream>>>(pc, P, occMask, pidxBuf);
    k_scan<<<NB*NBLKA, 256, 0, stream>>>(occMask, wordPrefix, pillars_f, slotCell);
    k_scatter<<<(NB*P+255)/256, 256, 0, stream>>>(P, pidxBuf, occMask, wordPrefix, slotCnt, idx16);
    k_write<<<NB*MAXPIL/PPB, 256, 0, stream>>>(pc, P, slotCell, slotCnt, idx16, out);
}